// Round 2
// baseline (243.197 us; speedup 1.0000x reference)
//
#include <hip/hip_runtime.h>
#include <hip/hip_bf16.h>

#define NPTS 12288
#define DD 128
#define CHUNKS 16
#define CHW (NPTS / CHUNKS)   // 768 cols per chunk
#define TILES (CHW / 64)      // 12 col-tiles of 64
#define NBANDS (NPTS / 64)    // 192 row bands

// descriptors pre-scaled by sqrt(10 * log2(e)) so MFMA result a = S*log2(e);
// then e^(S) = exp2(a) directly and argmax keys come from bits(exp2(a)).
#define PRESCALE 3.79828262f

typedef short bf16x8 __attribute__((ext_vector_type(8)));
typedef float f32x4 __attribute__((ext_vector_type(4)));

__device__ __forceinline__ float fast_exp2(float x) {
#if defined(__has_builtin)
#if __has_builtin(__builtin_amdgcn_exp2f)
  return __builtin_amdgcn_exp2f(x);
#else
  return exp2f(x);
#endif
#else
  return exp2f(x);
#endif
}

__device__ __forceinline__ short f2bf(float f) {  // RNE f32 -> bf16
  unsigned u = __float_as_uint(f);
  u += 0x7FFFu + ((u >> 16) & 1u);
  return (short)(u >> 16);
}

__device__ __forceinline__ unsigned umax(unsigned a, unsigned b) { return a > b ? a : b; }

// ---------------- fused prep (f32 -> scaled bf16) + exact positives ----------------
__global__ void k_prep_pos(const float* __restrict__ d0, const float* __restrict__ d1,
                           const int* __restrict__ c0, const int* __restrict__ c1,
                           short* __restrict__ o0, short* __restrict__ o1,
                           float* __restrict__ pos0, float* __restrict__ pos1) {
  if (blockIdx.x < 3072) {
    unsigned t = blockIdx.x * 256u + threadIdx.x;
    const unsigned half = (NPTS * DD) / 4;
    const float* src; short* dst; unsigned g;
    if (t < half) { src = d0; dst = o0; g = t; }
    else          { src = d1; dst = o1; g = t - half; }
    float4 v = *(const float4*)(src + (size_t)g * 4);
    short4 r;
    r.x = f2bf(v.x * PRESCALE); r.y = f2bf(v.y * PRESCALE);
    r.z = f2bf(v.z * PRESCALE); r.w = f2bf(v.w * PRESCALE);
    *(short4*)(dst + (size_t)g * 4) = r;
  } else {
    int w = (blockIdx.x - 3072) * 4 + (threadIdx.x >> 6);
    int lane = threadIdx.x & 63;
    const float *a, *b; float* out;
    if (w < NPTS) {
      int i = c0[w] > 0 ? c0[w] : 0;
      a = d0 + (size_t)w * DD; b = d1 + (size_t)i * DD; out = pos0 + w;
    } else {
      int m = w - NPTS;
      int i = c1[m] > 0 ? c1[m] : 0;
      a = d0 + (size_t)i * DD; b = d1 + (size_t)m * DD; out = pos1 + m;
    }
    float2 x = *(const float2*)(a + lane * 2);
    float2 y = *(const float2*)(b + lane * 2);
    float s = x.x * y.x + x.y * y.y;
    #pragma unroll
    for (int off = 1; off < 64; off <<= 1) s += __shfl_xor(s, off, 64);
    if (lane == 0) *out = 10.0f * s;
  }
}

// ---------------- main fused kernel ----------------
// wave = (band, chunk): 64 rows x 768 cols. A re-loaded per kk (L1-resident band)
// to keep live registers low enough for 3 blocks/CU.
// C-frag: col = lane&15, row = (lane>>4)*4 + reg   (m89/m91 layout, verified R1)
__launch_bounds__(256, 3)
__global__ void k_main(const short* __restrict__ d0b, const short* __restrict__ d1b,
                       uint2* __restrict__ colKV, uint2* __restrict__ rowKV) {
  const int widx = threadIdx.x >> 6;
  const int lane = threadIdx.x & 63;
  const int lo = lane & 15, hi = lane >> 4;
  const int chunk = blockIdx.x & (CHUNKS - 1);       // 4 waves share the chunk -> L1 reuse of B
  const int band = (blockIdx.x >> 4) * 4 + widx;     // 0..191
  const int row0 = band * 64;
  const int cbase = chunk * CHW;

  float rowsum[4][4];
  unsigned rowkey[4][4], rowcomp[4][4];
  #pragma unroll
  for (int i = 0; i < 4; i++)
    #pragma unroll
    for (int r = 0; r < 4; r++) {
      rowsum[i][r] = 0.f;
      rowkey[i][r] = 0u;
      rowcomp[i][r] = 0x3FFFu - (unsigned)(row0 + i * 16 + hi * 4 + r);
    }

  const short* ap = d0b + (size_t)row0 * DD;

  for (int t = 0; t < TILES; t++) {
    const int ct = cbase + t * 64;
    const short* bp = d1b + (size_t)ct * DD;

    f32x4 acc[4][4];
    #pragma unroll
    for (int i = 0; i < 4; i++)
      #pragma unroll
      for (int j = 0; j < 4; j++)
        acc[i][j] = (f32x4){0.f, 0.f, 0.f, 0.f};

    #pragma unroll
    for (int kk = 0; kk < 4; kk++) {
      bf16x8 af[4], bf[4];
      #pragma unroll
      for (int i = 0; i < 4; i++)
        af[i] = *(const bf16x8*)(ap + (size_t)(i * 16 + lo) * DD + kk * 32 + hi * 8);
      #pragma unroll
      for (int j = 0; j < 4; j++)
        bf[j] = *(const bf16x8*)(bp + (size_t)(j * 16 + lo) * DD + kk * 32 + hi * 8);
      #pragma unroll
      for (int j = 0; j < 4; j++)
        #pragma unroll
        for (int i = 0; i < 4; i++)
          acc[i][j] = __builtin_amdgcn_mfma_f32_16x16x32_bf16(af[i], bf[j], acc[i][j], 0, 0, 0);
    }

    // fused epilogue: e = e^S = exp2(a); keys from bits(e) (monotone), both directions
    #pragma unroll
    for (int j = 0; j < 4; j++) {
      float colsum = 0.f;
      unsigned colkey = 0u;
      const unsigned ccomp = 0x3FFFu - (unsigned)(ct + j * 16 + lo);
      #pragma unroll
      for (int i = 0; i < 4; i++)
        #pragma unroll
        for (int r = 0; r < 4; r++) {
          float e = fast_exp2(acc[i][j][r]);
          unsigned tb = __float_as_uint(e) & 0xFFFFC000u;
          rowkey[i][r] = umax(rowkey[i][r], tb | ccomp);
          colkey = umax(colkey, tb | rowcomp[i][r]);
          rowsum[i][r] += e;
          colsum += e;
        }
      colsum += __shfl_xor(colsum, 16, 64);
      colsum += __shfl_xor(colsum, 32, 64);
      colkey = umax(colkey, (unsigned)__shfl_xor((int)colkey, 16, 64));
      colkey = umax(colkey, (unsigned)__shfl_xor((int)colkey, 32, 64));
      if (hi == 0) {
        int c = ct + j * 16 + lo;
        colKV[(size_t)band * NPTS + c] = make_uint2(colkey, __float_as_uint(colsum));
      }
    }
  }

  // row partials: reduce over lo bits (cols), lanes with lo==0 write
  #pragma unroll
  for (int i = 0; i < 4; i++)
    #pragma unroll
    for (int r = 0; r < 4; r++) {
      float s = rowsum[i][r];
      unsigned k = rowkey[i][r];
      s += __shfl_xor(s, 1, 64); s += __shfl_xor(s, 2, 64);
      s += __shfl_xor(s, 4, 64); s += __shfl_xor(s, 8, 64);
      k = umax(k, (unsigned)__shfl_xor((int)k, 1, 64));
      k = umax(k, (unsigned)__shfl_xor((int)k, 2, 64));
      k = umax(k, (unsigned)__shfl_xor((int)k, 4, 64));
      k = umax(k, (unsigned)__shfl_xor((int)k, 8, 64));
      if (lo == 0) {
        int row = row0 + i * 16 + hi * 4 + r;
        rowKV[(size_t)chunk * NPTS + row] = make_uint2(k, __float_as_uint(s));
      }
    }
}

// ---------------- fused reduce: blocks 0..47 cols, 48..95 rows ----------------
__global__ void k_red(const uint2* __restrict__ colKV, const uint2* __restrict__ rowKV,
                      const float* __restrict__ pos0, const float* __restrict__ pos1,
                      const int* __restrict__ c0, const int* __restrict__ c1,
                      unsigned* __restrict__ best0, unsigned* __restrict__ best1,
                      float* __restrict__ l0part, float* __restrict__ l1part) {
  float v;
  if (blockIdx.x < 48) {
    int m = blockIdx.x * 256 + threadIdx.x;
    float s = 0.f; unsigned k = 0u;
    #pragma unroll 8
    for (int b = 0; b < NBANDS; b++) {
      uint2 kv = colKV[(size_t)b * NPTS + m];
      s += __uint_as_float(kv.y);
      k = umax(k, kv.x);
    }
    best1[m] = 0x3FFFu - (k & 0x3FFFu);
    v = (c1[m] >= 0) ? (logf(s) - pos1[m]) : 0.f;
  } else {
    int n = (blockIdx.x - 48) * 256 + threadIdx.x;
    float s = 0.f; unsigned k = 0u;
    #pragma unroll
    for (int c = 0; c < CHUNKS; c++) {
      uint2 kv = rowKV[(size_t)c * NPTS + n];
      s += __uint_as_float(kv.y);
      k = umax(k, kv.x);
    }
    best0[n] = 0x3FFFu - (k & 0x3FFFu);
    v = (c0[n] >= 0) ? (logf(s) - pos0[n]) : 0.f;
  }
  __shared__ float red[256];
  red[threadIdx.x] = v; __syncthreads();
  for (int st = 128; st > 0; st >>= 1) {
    if (threadIdx.x < st) red[threadIdx.x] += red[threadIdx.x + st];
    __syncthreads();
  }
  if (threadIdx.x == 0) {
    if (blockIdx.x < 48) l1part[blockIdx.x] = red[0];
    else                 l0part[blockIdx.x - 48] = red[0];
  }
}

// ---------------- final: losses + mutual-NN precision/recall ----------------
__global__ void k_final(const int* __restrict__ c0, const int* __restrict__ c1,
                        const float* __restrict__ lg0, const float* __restrict__ lg1,
                        const unsigned* __restrict__ best0, const unsigned* __restrict__ best1,
                        const float* __restrict__ l0part, const float* __restrict__ l1part,
                        float* __restrict__ out) {
  const int tid = threadIdx.x;
  float l0s = 0.f, l1s = 0.f;
  int m0c = 0, m1c = 0, tpc = 0, prc = 0;
  if (tid < 48) { l0s = l0part[tid]; l1s = l1part[tid]; }
  for (int n = tid; n < NPTS; n += 256) {
    int cc = c0[n];
    bool m0 = cc >= 0;
    if (m0) m0c++;
    int b0 = (int)best0[n];
    bool mutual = ((int)best1[b0] == n);
    bool pred = mutual && (lg0[n] >= 0.f) && (lg1[b0] >= 0.f);
    if (pred) { prc++; if (m0 && b0 == cc) tpc++; }
    if (c1[n] >= 0) m1c++;
  }
  __shared__ float sf[256];
  __shared__ int si[256];
  sf[tid] = l0s; __syncthreads();
  for (int st = 128; st > 0; st >>= 1) { if (tid < st) sf[tid] += sf[tid + st]; __syncthreads(); }
  float L0 = sf[0]; __syncthreads();
  sf[tid] = l1s; __syncthreads();
  for (int st = 128; st > 0; st >>= 1) { if (tid < st) sf[tid] += sf[tid + st]; __syncthreads(); }
  float L1 = sf[0]; __syncthreads();
  si[tid] = m0c; __syncthreads();
  for (int st = 128; st > 0; st >>= 1) { if (tid < st) si[tid] += si[tid + st]; __syncthreads(); }
  int M0 = si[0]; __syncthreads();
  si[tid] = m1c; __syncthreads();
  for (int st = 128; st > 0; st >>= 1) { if (tid < st) si[tid] += si[tid + st]; __syncthreads(); }
  int M1 = si[0]; __syncthreads();
  si[tid] = tpc; __syncthreads();
  for (int st = 128; st > 0; st >>= 1) { if (tid < st) si[tid] += si[tid + st]; __syncthreads(); }
  int TP = si[0]; __syncthreads();
  si[tid] = prc; __syncthreads();
  for (int st = 128; st > 0; st >>= 1) { if (tid < st) si[tid] += si[tid + st]; __syncthreads(); }
  int PR = si[0];
  if (tid == 0) {
    out[0] = L0 / (float)(M0 > 0 ? M0 : 1);
    out[1] = L1 / (float)(M1 > 0 ? M1 : 1);
    out[2] = (float)TP / (float)(PR > 0 ? PR : 1);
    out[3] = (float)TP / (float)(M0 > 0 ? M0 : 1);
  }
}

extern "C" void kernel_launch(void* const* d_in, const int* in_sizes, int n_in,
                              void* d_out, int out_size, void* d_ws, size_t ws_size,
                              hipStream_t stream) {
  const float* desc0 = (const float*)d_in[0];
  const float* desc1 = (const float*)d_in[1];
  const int* corr0   = (const int*)d_in[2];
  const int* corr1   = (const int*)d_in[3];
  const float* lg0   = (const float*)d_in[4];
  const float* lg1   = (const float*)d_in[5];
  float* out = (float*)d_out;

  char* w = (char*)d_ws;
  short* d0b   = (short*)(w);                   // 3,145,728 B
  short* d1b   = (short*)(w + 3145728);         // 3,145,728 B
  uint2* colKV = (uint2*)(w + 6291456);         // 18,874,368 B  [192][12288]
  uint2* rowKV = (uint2*)(w + 25165824);        //  1,572,864 B  [16][12288]
  float* pos0  = (float*)(w + 26738688);        //     49,152 B
  float* pos1  = (float*)(w + 26787840);        //     49,152 B
  unsigned* best0 = (unsigned*)(w + 26836992);  //     49,152 B
  unsigned* best1 = (unsigned*)(w + 26886144);  //     49,152 B
  float* l0part = (float*)(w + 26935296);       //        192 B
  float* l1part = (float*)(w + 26935488);       //        192 B

  k_prep_pos<<<9216, 256, 0, stream>>>(desc0, desc1, corr0, corr1, d0b, d1b, pos0, pos1);
  k_main<<<768, 256, 0, stream>>>(d0b, d1b, colKV, rowKV);
  k_red<<<96, 256, 0, stream>>>(colKV, rowKV, pos0, pos1, corr0, corr1, best0, best1, l0part, l1part);
  k_final<<<1, 256, 0, stream>>>(corr0, corr1, lg0, lg1, best0, best1, l0part, l1part, out);
}

// Round 3
// 176.911 us; speedup vs baseline: 1.3747x; 1.3747x over previous
//
#include <hip/hip_runtime.h>
#include <hip/hip_bf16.h>

#define NPTS 12288
#define DD 128
#define CHUNKS 16
#define CHW (NPTS / CHUNKS)   // 768 cols per chunk
#define TILES (CHW / 64)      // 12 col-tiles of 64
#define NBANDS (NPTS / 64)    // 192 row bands

// descriptors pre-scaled by sqrt(10 * log2(e)) so MFMA result a = S*log2(e);
// then e^S = exp2(a) directly and argmax keys come from bits(exp2(a)).
#define PRESCALE 3.79828262f

typedef short bf16x8 __attribute__((ext_vector_type(8)));
typedef float f32x4 __attribute__((ext_vector_type(4)));

__device__ __forceinline__ float fast_exp2(float x) {
#if defined(__has_builtin)
#if __has_builtin(__builtin_amdgcn_exp2f)
  return __builtin_amdgcn_exp2f(x);
#else
  return exp2f(x);
#endif
#else
  return exp2f(x);
#endif
}

__device__ __forceinline__ short f2bf(float f) {  // RNE f32 -> bf16
  unsigned u = __float_as_uint(f);
  u += 0x7FFFu + ((u >> 16) & 1u);
  return (short)(u >> 16);
}

__device__ __forceinline__ unsigned umax(unsigned a, unsigned b) { return a > b ? a : b; }

// ---------------- fused prep (f32 -> scaled bf16) + exact positives ----------------
__global__ void k_prep_pos(const float* __restrict__ d0, const float* __restrict__ d1,
                           const int* __restrict__ c0, const int* __restrict__ c1,
                           short* __restrict__ o0, short* __restrict__ o1,
                           float* __restrict__ pos0, float* __restrict__ pos1) {
  if (blockIdx.x < 3072) {
    unsigned t = blockIdx.x * 256u + threadIdx.x;
    const unsigned half = (NPTS * DD) / 4;
    const float* src; short* dst; unsigned g;
    if (t < half) { src = d0; dst = o0; g = t; }
    else          { src = d1; dst = o1; g = t - half; }
    float4 v = *(const float4*)(src + (size_t)g * 4);
    short4 r;
    r.x = f2bf(v.x * PRESCALE); r.y = f2bf(v.y * PRESCALE);
    r.z = f2bf(v.z * PRESCALE); r.w = f2bf(v.w * PRESCALE);
    *(short4*)(dst + (size_t)g * 4) = r;
  } else {
    int w = (blockIdx.x - 3072) * 4 + (threadIdx.x >> 6);
    int lane = threadIdx.x & 63;
    const float *a, *b; float* out;
    if (w < NPTS) {
      int i = c0[w] > 0 ? c0[w] : 0;
      a = d0 + (size_t)w * DD; b = d1 + (size_t)i * DD; out = pos0 + w;
    } else {
      int m = w - NPTS;
      int i = c1[m] > 0 ? c1[m] : 0;
      a = d0 + (size_t)i * DD; b = d1 + (size_t)m * DD; out = pos1 + m;
    }
    float2 x = *(const float2*)(a + lane * 2);
    float2 y = *(const float2*)(b + lane * 2);
    float s = x.x * y.x + x.y * y.y;
    #pragma unroll
    for (int off = 1; off < 64; off <<= 1) s += __shfl_xor(s, off, 64);
    if (lane == 0) *out = 10.0f * s;
  }
}

// ---------------- main fused kernel ----------------
// wave = (band, chunk): 64 rows x 768 cols, MFMA 16x16x32 bf16, fused exp/argmax epilogue.
// A fragments hoisted for the whole kernel (R1 codegen: 128 VGPR, zero spill).
// C-frag: col = lane&15, row = (lane>>4)*4 + reg   (m89/m91 layout, verified R1)
__launch_bounds__(256, 2)
__global__ void k_main(const short* __restrict__ d0b, const short* __restrict__ d1b,
                       uint2* __restrict__ colKV, uint2* __restrict__ rowKV) {
  const int widx = threadIdx.x >> 6;
  const int lane = threadIdx.x & 63;
  const int lo = lane & 15, hi = lane >> 4;
  const int chunk = blockIdx.x & (CHUNKS - 1);       // 4 waves share the chunk -> L1 reuse of B
  const int band = (blockIdx.x >> 4) * 4 + widx;     // 0..191
  const int row0 = band * 64;
  const int cbase = chunk * CHW;

  // A fragments for this wave's 64 rows, all of K=128 (held for whole kernel)
  bf16x8 af[4][4];
  #pragma unroll
  for (int i = 0; i < 4; i++)
    #pragma unroll
    for (int kk = 0; kk < 4; kk++)
      af[i][kk] = *(const bf16x8*)(d0b + (size_t)(row0 + i * 16 + lo) * DD + kk * 32 + hi * 8);

  float rowsum[4][4];
  unsigned rowkey[4][4], rowcomp[4][4];
  #pragma unroll
  for (int i = 0; i < 4; i++)
    #pragma unroll
    for (int r = 0; r < 4; r++) {
      rowsum[i][r] = 0.f;
      rowkey[i][r] = 0u;
      rowcomp[i][r] = 0x3FFFu - (unsigned)(row0 + i * 16 + hi * 4 + r);
    }

  for (int t = 0; t < TILES; t++) {
    const int ct = cbase + t * 64;
    const short* bp = d1b + (size_t)ct * DD;

    f32x4 acc[4][4];
    #pragma unroll
    for (int i = 0; i < 4; i++)
      #pragma unroll
      for (int j = 0; j < 4; j++)
        acc[i][j] = (f32x4){0.f, 0.f, 0.f, 0.f};

    #pragma unroll
    for (int kk = 0; kk < 4; kk++) {
      bf16x8 bf[4];
      #pragma unroll
      for (int j = 0; j < 4; j++)
        bf[j] = *(const bf16x8*)(bp + (size_t)(j * 16 + lo) * DD + kk * 32 + hi * 8);
      #pragma unroll
      for (int j = 0; j < 4; j++)
        #pragma unroll
        for (int i = 0; i < 4; i++)
          acc[i][j] = __builtin_amdgcn_mfma_f32_16x16x32_bf16(af[i][kk], bf[j], acc[i][j], 0, 0, 0);
    }

    // fused epilogue: e = e^S = exp2(a); keys from bits(e) (monotone), both directions
    #pragma unroll
    for (int j = 0; j < 4; j++) {
      float colsum = 0.f;
      unsigned colkey = 0u;
      const unsigned ccomp = 0x3FFFu - (unsigned)(ct + j * 16 + lo);
      #pragma unroll
      for (int i = 0; i < 4; i++)
        #pragma unroll
        for (int r = 0; r < 4; r++) {
          float e = fast_exp2(acc[i][j][r]);
          unsigned tb = __float_as_uint(e) & 0xFFFFC000u;
          rowkey[i][r] = umax(rowkey[i][r], tb | ccomp);
          colkey = umax(colkey, tb | rowcomp[i][r]);
          rowsum[i][r] += e;
          colsum += e;
        }
      colsum += __shfl_xor(colsum, 16, 64);
      colsum += __shfl_xor(colsum, 32, 64);
      colkey = umax(colkey, (unsigned)__shfl_xor((int)colkey, 16, 64));
      colkey = umax(colkey, (unsigned)__shfl_xor((int)colkey, 32, 64));
      if (hi == 0) {
        int c = ct + j * 16 + lo;
        colKV[(size_t)band * NPTS + c] = make_uint2(colkey, __float_as_uint(colsum));
      }
    }
  }

  // row partials: reduce over lo bits (cols), lanes with lo==0 write
  #pragma unroll
  for (int i = 0; i < 4; i++)
    #pragma unroll
    for (int r = 0; r < 4; r++) {
      float s = rowsum[i][r];
      unsigned k = rowkey[i][r];
      s += __shfl_xor(s, 1, 64); s += __shfl_xor(s, 2, 64);
      s += __shfl_xor(s, 4, 64); s += __shfl_xor(s, 8, 64);
      k = umax(k, (unsigned)__shfl_xor((int)k, 1, 64));
      k = umax(k, (unsigned)__shfl_xor((int)k, 2, 64));
      k = umax(k, (unsigned)__shfl_xor((int)k, 4, 64));
      k = umax(k, (unsigned)__shfl_xor((int)k, 8, 64));
      if (lo == 0) {
        int row = row0 + i * 16 + hi * 4 + r;
        rowKV[(size_t)chunk * NPTS + row] = make_uint2(k, __float_as_uint(s));
      }
    }
}

// ---------------- fused reduce: blocks 0..47 cols, 48..95 rows ----------------
__global__ void k_red(const uint2* __restrict__ colKV, const uint2* __restrict__ rowKV,
                      const float* __restrict__ pos0, const float* __restrict__ pos1,
                      const int* __restrict__ c0, const int* __restrict__ c1,
                      unsigned* __restrict__ best0, unsigned* __restrict__ best1,
                      float* __restrict__ l0part, float* __restrict__ l1part) {
  float v;
  if (blockIdx.x < 48) {
    int m = blockIdx.x * 256 + threadIdx.x;
    float s = 0.f; unsigned k = 0u;
    #pragma unroll 8
    for (int b = 0; b < NBANDS; b++) {
      uint2 kv = colKV[(size_t)b * NPTS + m];
      s += __uint_as_float(kv.y);
      k = umax(k, kv.x);
    }
    best1[m] = 0x3FFFu - (k & 0x3FFFu);
    v = (c1[m] >= 0) ? (logf(s) - pos1[m]) : 0.f;
  } else {
    int n = (blockIdx.x - 48) * 256 + threadIdx.x;
    float s = 0.f; unsigned k = 0u;
    #pragma unroll
    for (int c = 0; c < CHUNKS; c++) {
      uint2 kv = rowKV[(size_t)c * NPTS + n];
      s += __uint_as_float(kv.y);
      k = umax(k, kv.x);
    }
    best0[n] = 0x3FFFu - (k & 0x3FFFu);
    v = (c0[n] >= 0) ? (logf(s) - pos0[n]) : 0.f;
  }
  __shared__ float red[256];
  red[threadIdx.x] = v; __syncthreads();
  for (int st = 128; st > 0; st >>= 1) {
    if (threadIdx.x < st) red[threadIdx.x] += red[threadIdx.x + st];
    __syncthreads();
  }
  if (threadIdx.x == 0) {
    if (blockIdx.x < 48) l1part[blockIdx.x] = red[0];
    else                 l0part[blockIdx.x - 48] = red[0];
  }
}

// ---------------- final: losses + mutual-NN precision/recall ----------------
__global__ void k_final(const int* __restrict__ c0, const int* __restrict__ c1,
                        const float* __restrict__ lg0, const float* __restrict__ lg1,
                        const unsigned* __restrict__ best0, const unsigned* __restrict__ best1,
                        const float* __restrict__ l0part, const float* __restrict__ l1part,
                        float* __restrict__ out) {
  const int tid = threadIdx.x;
  float l0s = 0.f, l1s = 0.f;
  int m0c = 0, m1c = 0, tpc = 0, prc = 0;
  if (tid < 48) { l0s = l0part[tid]; l1s = l1part[tid]; }
  for (int n = tid; n < NPTS; n += 256) {
    int cc = c0[n];
    bool m0 = cc >= 0;
    if (m0) m0c++;
    int b0 = (int)best0[n];
    bool mutual = ((int)best1[b0] == n);
    bool pred = mutual && (lg0[n] >= 0.f) && (lg1[b0] >= 0.f);
    if (pred) { prc++; if (m0 && b0 == cc) tpc++; }
    if (c1[n] >= 0) m1c++;
  }
  __shared__ float sf[256];
  __shared__ int si[256];
  sf[tid] = l0s; __syncthreads();
  for (int st = 128; st > 0; st >>= 1) { if (tid < st) sf[tid] += sf[tid + st]; __syncthreads(); }
  float L0 = sf[0]; __syncthreads();
  sf[tid] = l1s; __syncthreads();
  for (int st = 128; st > 0; st >>= 1) { if (tid < st) sf[tid] += sf[tid + st]; __syncthreads(); }
  float L1 = sf[0]; __syncthreads();
  si[tid] = m0c; __syncthreads();
  for (int st = 128; st > 0; st >>= 1) { if (tid < st) si[tid] += si[tid + st]; __syncthreads(); }
  int M0 = si[0]; __syncthreads();
  si[tid] = m1c; __syncthreads();
  for (int st = 128; st > 0; st >>= 1) { if (tid < st) si[tid] += si[tid + st]; __syncthreads(); }
  int M1 = si[0]; __syncthreads();
  si[tid] = tpc; __syncthreads();
  for (int st = 128; st > 0; st >>= 1) { if (tid < st) si[tid] += si[tid + st]; __syncthreads(); }
  int TP = si[0]; __syncthreads();
  si[tid] = prc; __syncthreads();
  for (int st = 128; st > 0; st >>= 1) { if (tid < st) si[tid] += si[tid + st]; __syncthreads(); }
  int PR = si[0];
  if (tid == 0) {
    out[0] = L0 / (float)(M0 > 0 ? M0 : 1);
    out[1] = L1 / (float)(M1 > 0 ? M1 : 1);
    out[2] = (float)TP / (float)(PR > 0 ? PR : 1);
    out[3] = (float)TP / (float)(M0 > 0 ? M0 : 1);
  }
}

extern "C" void kernel_launch(void* const* d_in, const int* in_sizes, int n_in,
                              void* d_out, int out_size, void* d_ws, size_t ws_size,
                              hipStream_t stream) {
  const float* desc0 = (const float*)d_in[0];
  const float* desc1 = (const float*)d_in[1];
  const int* corr0   = (const int*)d_in[2];
  const int* corr1   = (const int*)d_in[3];
  const float* lg0   = (const float*)d_in[4];
  const float* lg1   = (const float*)d_in[5];
  float* out = (float*)d_out;

  char* w = (char*)d_ws;
  short* d0b   = (short*)(w);                   // 3,145,728 B
  short* d1b   = (short*)(w + 3145728);         // 3,145,728 B
  uint2* colKV = (uint2*)(w + 6291456);         // 18,874,368 B  [192][12288]
  uint2* rowKV = (uint2*)(w + 25165824);        //  1,572,864 B  [16][12288]
  float* pos0  = (float*)(w + 26738688);        //     49,152 B
  float* pos1  = (float*)(w + 26787840);        //     49,152 B
  unsigned* best0 = (unsigned*)(w + 26836992);  //     49,152 B
  unsigned* best1 = (unsigned*)(w + 26886144);  //     49,152 B
  float* l0part = (float*)(w + 26935296);       //        192 B
  float* l1part = (float*)(w + 26935488);       //        192 B

  k_prep_pos<<<9216, 256, 0, stream>>>(desc0, desc1, corr0, corr1, d0b, d1b, pos0, pos1);
  k_main<<<768, 256, 0, stream>>>(d0b, d1b, colKV, rowKV);
  k_red<<<96, 256, 0, stream>>>(colKV, rowKV, pos0, pos1, corr0, corr1, best0, best1, l0part, l1part);
  k_final<<<1, 256, 0, stream>>>(corr0, corr1, lg0, lg1, best0, best1, l0part, l1part, out);
}